// Round 11
// baseline (567.540 us; speedup 1.0000x reference)
//
#include <hip/hip_runtime.h>
#include <math.h>

#define B_   256
#define S_   4
#define W1_  64
#define W2_  128
#define D_   300
#define HID_ 4

typedef float          fx4   __attribute__((ext_vector_type(4)));
typedef short          s16x8 __attribute__((ext_vector_type(8)));
typedef unsigned int   ux4   __attribute__((ext_vector_type(4)));

__device__ __forceinline__ unsigned bf16_rne(float x) {
    unsigned u = __float_as_uint(x);
    return (u + 0x7FFFu + ((u >> 16) & 1u)) >> 16;   // bf16 in low 16 bits
}

// Split 8 consecutive-k f32 (two fx4) into hi/lo bf16x8 MFMA fragments.
// PROVEN bit-trick version (absmax 0 in R4/R5/R8/R9). R10's v_cvt_pk
// variant broke correctness — reverted, never again without isolation.
__device__ __forceinline__ void cvt8(const fx4 x0, const fx4 x1, s16x8& hi, s16x8& lo) {
    ux4 hu, lu;
#pragma unroll
    for (int p = 0; p < 4; ++p) {
        float a = (p < 2) ? x0[2 * p]     : x1[2 * p - 4];
        float b = (p < 2) ? x0[2 * p + 1] : x1[2 * p - 3];
        unsigned ha = bf16_rne(a), hb = bf16_rne(b);
        float haf = __uint_as_float(ha << 16);
        float hbf = __uint_as_float(hb << 16);
        unsigned la = bf16_rne(a - haf), lb = bf16_rne(b - hbf);
        hu[p] = ha | (hb << 16);
        lu[p] = la | (lb << 16);
    }
    hi = __builtin_bit_cast(s16x8, hu);
    lo = __builtin_bit_cast(s16x8, lu);
}

// Inline-asm 16B load, compile-time byte offset. "=v" output cannot be
// dissolved by regalloc (R5-R9 lesson: plain loads get sunk next to use).
template <int OFF>
__device__ __forceinline__ void gload(fx4& d, const float* p) {
    asm volatile("global_load_dwordx4 %0, %1, off offset:%c2"
                 : "=v"(d) : "v"(p), "i"(OFF));
}

#define FENCE  __builtin_amdgcn_sched_barrier(0)
#define WAITN(N) do { asm volatile("s_waitcnt vmcnt(" #N ")" ::: "memory"); FENCE; } while (0)

// Latency-chain-collapsed MFMA similarity-count (R10 structure, R9 numerics).
// 16x16 tile per wave -> 32 waves/slot (8192 blocks), 4 loads/K-step,
// depth-4 asm pipeline (16 outstanding, vmcnt(12) steady). 16 fx4 buffers
// = 64 VGPR keeps total pressure ~100-115, safely under the 128 cap from
// launch_bounds(256,4) -> no spill -> vmcnt ledger stays exact.
__global__ __launch_bounds__(256, 4) void sim_count_mfma(
    const float* __restrict__ t1, const float* __restrict__ t2,
    const int* __restrict__ m1, const int* __restrict__ m2,
    const float* __restrict__ thr_p, int* __restrict__ cnt)
{
    const int slot = blockIdx.x >> 3;
    const int p8   = blockIdx.x & 7;        // part: 2 rt-pairs x 4 ct-pairs
    const int tid  = threadIdx.x;
    const int l    = tid & 63;
    const int w    = tid >> 6;
    const int rt   = (p8 >> 2) * 2 + (w >> 1);   // 0..3  (A row-tile)
    const int ct   = (p8 & 3) * 2 + (w & 1);     // 0..7  (B col-tile)
    const int lr   = l & 15;
    const int lg8  = (l >> 4) * 8;          // frag k-offset within 32-step

    const float* aP = t1 + (size_t)slot * W1_ * D_ + (size_t)(rt * 16 + lr) * D_ + lg8;
    const float* bP = t2 + (size_t)slot * W2_ * D_ + (size_t)(ct * 16 + lr) * D_ + lg8;

    fx4 acc; acc[0] = 0.f; acc[1] = 0.f; acc[2] = 0.f; acc[3] = 0.f;

    // 4 named buffer sets — no runtime indexing (rule #20).
    fx4 S0a0, S0a1, S0b0, S0b1, S1a0, S1a1, S1b0, S1b1,
        S2a0, S2a1, S2b0, S2b1, S3a0, S3a1, S3b0, S3b1;

#define ISSUE(T, S) do { \
    gload<(T)*128>(S##a0, aP); gload<(T)*128+16>(S##a1, aP); \
    gload<(T)*128>(S##b0, bP); gload<(T)*128+16>(S##b1, bP); FENCE; } while (0)

    auto compute = [&](fx4& a0, fx4& a1, fx4& b0, fx4& b1) {
        s16x8 ah, al, bh, bl;
        cvt8(a0, a1, ah, al);
        cvt8(b0, b1, bh, bl);
        acc = __builtin_amdgcn_mfma_f32_16x16x32_bf16(ah, bh, acc, 0, 0, 0);
        acc = __builtin_amdgcn_mfma_f32_16x16x32_bf16(ah, bl, acc, 0, 0, 0);
        acc = __builtin_amdgcn_mfma_f32_16x16x32_bf16(al, bh, acc, 0, 0, 0);
    };

    // Prologue: fill all 4 buffers (16 outstanding). Tiles T0..T8 are fully
    // valid k (max k = 256+24+7 = 287 < 300); T9 (k288..299) is the tail.
    ISSUE(0, S0); ISSUE(1, S1); ISSUE(2, S2); ISSUE(3, S3);

    WAITN(12); compute(S0a0, S0a1, S0b0, S0b1); FENCE; ISSUE(4, S0);  // T0
    WAITN(12); compute(S1a0, S1a1, S1b0, S1b1); FENCE; ISSUE(5, S1);  // T1
    WAITN(12); compute(S2a0, S2a1, S2b0, S2b1); FENCE; ISSUE(6, S2);  // T2
    WAITN(12); compute(S3a0, S3a1, S3b0, S3b1); FENCE; ISSUE(7, S3);  // T3
    WAITN(12); compute(S0a0, S0a1, S0b0, S0b1); FENCE; ISSUE(8, S0);  // T4
    WAITN(12); compute(S1a0, S1a1, S1b0, S1b1); FENCE;                // T5
    {   // Tail issue (T9 -> S1): per-lane clamped in-row pointers, never OOB.
        const float* aRow = aP - lg8;
        const float* bRow = bP - lg8;
        const int o1 = (lg8 == 8) ? 296 : 288;
        const int o2 = (lg8 == 0) ? 292 : 288;
        gload<0>(S1a0, aRow + o1);
        gload<0>(S1a1, aRow + o2);
        gload<0>(S1b0, bRow + o1);
        gload<0>(S1b1, bRow + o2);
        FENCE;
    }
    WAITN(12); compute(S2a0, S2a1, S2b0, S2b1); FENCE;                // T6
    WAITN(8);  compute(S3a0, S3a1, S3b0, S3b1); FENCE;                // T7
    WAITN(4);  compute(S0a0, S0a1, S0b0, S0b1); FENCE;                // T8
    WAITN(0);                                                         // T9 in
    {
        const bool k1 = (lg8 <= 8);   // first fx4 valid for lg8 in {0,8}
        const bool k2 = (lg8 == 0);   // second fx4 valid only for lg8==0
#pragma unroll
        for (int e = 0; e < 4; ++e) {
            S1a0[e] = k1 ? S1a0[e] : 0.f;  S1a1[e] = k2 ? S1a1[e] : 0.f;
            S1b0[e] = k1 ? S1b0[e] : 0.f;  S1b1[e] = k2 ? S1b1[e] : 0.f;
        }
        compute(S1a0, S1a1, S1b0, S1b1);                              // T9
    }

    // Masked threshold count. C/D: col = ct*16 + (l&15), row = rt*16 + (l>>4)*4 + r.
    const float thr = *thr_p;
    const int bm = m2[slot * W2_ + ct * 16 + lr];
    int lc = 0;
#pragma unroll
    for (int r = 0; r < 4; ++r) {
        const int am = m1[slot * W1_ + rt * 16 + (l >> 4) * 4 + r];
        lc += ((acc[r] >= thr) & (am != 0) & (bm != 0)) ? 1 : 0;
    }
#pragma unroll
    for (int o = 32; o > 0; o >>= 1) lc += __shfl_down(lc, o);
    if (l == 0) atomicAdd(&cnt[slot], lc);   // device-scope, cross-XCD safe
#undef ISSUE
}

// Finalize: norm = cnt / nA (nA recomputed from m1), then MLP head.
__global__ __launch_bounds__(256) void finalize_head(
    const int* __restrict__ cnt, const int* __restrict__ m1,
    const float* __restrict__ Wh,   // (S, HID) row-major
    const float* __restrict__ Ws,   // (HID, 1)
    float* __restrict__ out)
{
    int b = blockIdx.x * blockDim.x + threadIdx.x;
    if (b >= B_) return;
    float n[4];
#pragma unroll
    for (int s = 0; s < 4; ++s) {
        const int slot = b * 4 + s;
        int nA = 0;
        const int4* mp = (const int4*)(m1 + slot * W1_);
#pragma unroll
        for (int g = 0; g < 16; ++g) {
            int4 v = mp[g];
            nA += (v.x != 0) + (v.y != 0) + (v.z != 0) + (v.w != 0);
        }
        const float divisor = (nA == 0) ? 1e-7f : (float)nA;
        n[s] = (float)cnt[slot] / divisor;
    }
    float score = 0.f;
#pragma unroll
    for (int j = 0; j < HID_; ++j) {
        float h = n[0] * Wh[0 * HID_ + j] + n[1] * Wh[1 * HID_ + j]
                + n[2] * Wh[2 * HID_ + j] + n[3] * Wh[3 * HID_ + j];
        h = tanhf(h);
        score += h * Ws[j];
    }
    out[b] = 1.f / (1.f + expf(-score));
}

extern "C" void kernel_launch(void* const* d_in, const int* in_sizes, int n_in,
                              void* d_out, int out_size, void* d_ws, size_t ws_size,
                              hipStream_t stream)
{
    const float* t1  = (const float*)d_in[0];
    const float* t2  = (const float*)d_in[1];
    const int*   m1  = (const int*)d_in[2];
    const int*   m2  = (const int*)d_in[3];
    const float* thr = (const float*)d_in[4];
    const float* Wh  = (const float*)d_in[5];
    const float* Ws  = (const float*)d_in[6];
    float* out = (float*)d_out;
    int*   cnt = (int*)d_ws;   // 1024 ints

    hipMemsetAsync(cnt, 0, B_ * S_ * sizeof(int), stream);
    sim_count_mfma<<<B_ * S_ * 8, 256, 0, stream>>>(t1, t2, m1, m2, thr, cnt);
    finalize_head<<<1, 256, 0, stream>>>(cnt, m1, Wh, Ws, out);
}